// Round 10
// baseline (648.918 us; speedup 1.0000x reference)
//
#include <hip/hip_runtime.h>

#define EMB 128
#define HRANGE 16384       // nodes per histogram range (64 KB LDS, packed cnt|deg)
#define HSTRIPE_LOG 13     // 8192 edges per stripe
#define UN 4

typedef __attribute__((ext_vector_type(8))) short bf16x8;
typedef __attribute__((ext_vector_type(4))) float f32x4;

__device__ inline unsigned short f2bf(float f) {
  unsigned u = __float_as_uint(f);
  return (unsigned short)((u + 0x7FFF + ((u >> 16) & 1)) >> 16);   // RNE
}
__device__ inline float bf2f(unsigned short s) {
  return __uint_as_float(((unsigned)s) << 16);
}

// ---------- CSR build via LDS histograms, packed cnt|deg (no global atomics) ----
__global__ __launch_bounds__(256) void k_hist(const int* __restrict__ row,
    const int* __restrict__ col, unsigned short* __restrict__ degP,
    unsigned short* __restrict__ cntP, int* __restrict__ ord, int E, int N) {
  __shared__ unsigned int hw[HRANGE];
  int s = blockIdx.x, r = blockIdx.y;
  int nlo = r * HRANGE;
  for (int t = threadIdx.x; t < HRANGE; t += 256) hw[t] = 0u;
  __syncthreads();
  int k0 = s << HSTRIPE_LOG;
  int k1 = min(E, k0 + (1 << HSTRIPE_LOG));
  for (int k = k0 + threadIdx.x; k < k1; k += 256) {
    int c = col[k] - nlo;
    if ((unsigned)c < HRANGE)
      ord[k] = (int)(atomicAdd(&hw[c], 1u) & 0xFFFFu);
    int rr = row[k] - nlo;
    if ((unsigned)rr < HRANGE)
      atomicAdd(&hw[rr], 0x10000u);
  }
  __syncthreads();
  for (int t = threadIdx.x; t < HRANGE; t += 256) {
    int node = nlo + t;
    if (node < N) {
      unsigned w = hw[t];
      cntP[(size_t)s * N + node] = (unsigned short)(w & 0xFFFFu);
      degP[(size_t)s * N + node] = (unsigned short)(w >> 16);
    }
  }
}

__global__ __launch_bounds__(256) void k_colreduce(unsigned short* __restrict__ cntP,
    int* __restrict__ cnt, int N, int ns) {
  int i = blockIdx.x * 256 + threadIdx.x;
  if (i < N) {
    int ssum = 0;
    for (int s = 0; s < ns; ++s) {
      int v = cntP[(size_t)s * N + i];
      cntP[(size_t)s * N + i] = (unsigned short)ssum;
      ssum += v;
    }
    cnt[i] = ssum;
  }
}

__global__ __launch_bounds__(256) void k_dinv(const unsigned short* __restrict__ degP,
    float* __restrict__ dinv, int N, int ns) {
  int i = blockIdx.x * 256 + threadIdx.x;
  if (i < N) {
    int d = 0;
    for (int s = 0; s < ns; ++s) d += degP[(size_t)s * N + i];
    float df = (float)(d == 0 ? 1 : d);
    dinv[i] = 1.0f / sqrtf(df);
  }
}

// ---------- multi-block exclusive scan ----------
__global__ __launch_bounds__(256) void k_scan_local(const int* __restrict__ cnt,
    int* __restrict__ startp, int* __restrict__ partial, int N) {
  __shared__ int lds[256];
  int tid = threadIdx.x;
  int i = blockIdx.x * 256 + tid;
  int v = (i < N) ? cnt[i] : 0;
  lds[tid] = v;
  __syncthreads();
#pragma unroll
  for (int off = 1; off < 256; off <<= 1) {
    int t = (tid >= off) ? lds[tid - off] : 0;
    __syncthreads();
    lds[tid] += t;
    __syncthreads();
  }
  if (i < N) startp[i] = lds[tid] - v;
  if (tid == 255) partial[blockIdx.x] = lds[255];
}

__global__ void k_scan_part(int* __restrict__ partial, int nb) {
  __shared__ int lds[1024];
  int tid = threadIdx.x;
  int v = (tid < nb) ? partial[tid] : 0;
  lds[tid] = v;
  __syncthreads();
  for (int off = 1; off < 1024; off <<= 1) {
    int t = (tid >= off) ? lds[tid - off] : 0;
    __syncthreads();
    lds[tid] += t;
    __syncthreads();
  }
  if (tid < nb) partial[tid] = lds[tid] - v;
}

__global__ __launch_bounds__(256) void k_scan_add(int* __restrict__ startp,
    const int* __restrict__ partial, int N, int E) {
  int i = blockIdx.x * 256 + threadIdx.x;
  if (i < N) startp[i] += partial[blockIdx.x];
  if (i == 0) startp[N] = E;
}

// emeta pack: m.x = (src<<9) | bond  (src*512 = h-row byte offset; bond in low 4)
__global__ __launch_bounds__(256) void k_fill(const int* __restrict__ row,
    const int* __restrict__ col, const int* __restrict__ attr,
    const int* __restrict__ startp, const unsigned short* __restrict__ cntP,
    const int* __restrict__ ord, const float* __restrict__ dinv,
    int2* __restrict__ emeta, int E, int N) {
  int k = blockIdx.x * 256 + threadIdx.x;
  if (k < E) {
    int r = row[k], c = col[k];
    int s = k >> HSTRIPE_LOG;
    int pos = startp[c] + (int)cntP[(size_t)s * N + c] + ord[k];
    int2 m;
    m.x = (r << 9) | attr[k];
    m.y = __float_as_int(dinv[r] * dinv[c]);
    emeta[pos] = m;
  }
}

// ---------- W split ----------
__global__ __launch_bounds__(256) void k_wsplit(const float* __restrict__ W,
    unsigned short* __restrict__ Wt, int total) {
  int t = blockIdx.x * 256 + threadIdx.x;   // t = (l*128 + k)*128 + n
  if (t >= total) return;
  int n = t & 127, k = (t >> 7) & 127, l = t >> 14;
  float v = W[t];
  unsigned short hi = f2bf(v);
  unsigned short lo = f2bf(v - bf2f(hi));
  size_t base = (size_t)l * 256 * EMB;
  Wt[base + (size_t)n * EMB + k] = hi;
  Wt[base + (size_t)(128 + n) * EMB + k] = lo;
}

// ---------- aggregation ----------
// MODE 0: real (slim: preshifted meta, unchecked full-8 iters, masked tail once)
// MODE 2: PROBE gather-only — synthesized random src, acc+=hv, no meta/ev/fma.
template<int L0, int MODE>
__global__ __launch_bounds__(256) void k_agg(const float* __restrict__ h,
    const int* __restrict__ xv, const float* __restrict__ atom_emb,
    const int* __restrict__ startp, const int2* __restrict__ emeta,
    const float* __restrict__ bond_emb, unsigned short* __restrict__ Ahi,
    unsigned short* __restrict__ Alo, int N, int BV) {
  __shared__ float eb_lds[16 * EMB];           // bond table, 8 KB
  for (int t = threadIdx.x; t < BV * (EMB / 4); t += 256)
    reinterpret_cast<float4*>(eb_lds)[t] =
        reinterpret_cast<const float4*>(bond_emb)[t];
  __syncthreads();

  int wave = threadIdx.x >> 6, lane = threadIdx.x & 63;
  int half = lane >> 5, sl = lane & 31;
  int idx = blockIdx.x * 4 + wave;
  int node;
  if constexpr (MODE == 2) {              // 2-pass amplified probe
    if (idx >= 2 * N) return;
    node = (idx < N) ? idx : idx - N;
  } else {
    node = idx;
    if (node >= N) return;
  }
  int s = startp[node], e = startp[node + 1];
  int deg = e - s;
  float4 acc = make_float4(0.f, 0.f, 0.f, 0.f);
  const char* hb = (const char*)h;
  const char* eb = (const char*)eb_lds;
  int slb = sl << 4;

  if constexpr (MODE == 2) {
    int npair = (deg + 1) >> 1;
    for (int step = 0; step < npair; step += UN) {
      float4 hv[UN];
#pragma unroll
      for (int u = 0; u < UN; ++u) {
        unsigned pp = (unsigned)(s + 2 * (step + u) + half);
        unsigned src = __umulhi(pp * 2654435761u, (unsigned)N);
        hv[u] = *reinterpret_cast<const float4*>(hb + ((size_t)src << 9) + slb);
      }
#pragma unroll
      for (int u = 0; u < UN; ++u) {
        acc.x += hv[u].x; acc.y += hv[u].y; acc.z += hv[u].z; acc.w += hv[u].w;
      }
    }
  } else {
    int nfull = deg >> 3;                 // unchecked 8-edge iterations
    int p = s;
    for (int it = 0; it < nfull; ++it, p += 8) {
      int2 m[UN];
#pragma unroll
      for (int u = 0; u < UN; ++u) m[u] = emeta[p + 2 * u + half];
      float4 hv[UN];
#pragma unroll
      for (int u = 0; u < UN; ++u) {
        if constexpr (L0) {
          int xi = xv[m[u].x >> 9];
          hv[u] = *(reinterpret_cast<const float4*>(atom_emb + (size_t)xi * EMB) + sl);
        } else {
          hv[u] = *reinterpret_cast<const float4*>(hb + (m[u].x & 0xFFFFFE00u) + slb);
        }
      }
#pragma unroll
      for (int u = 0; u < UN; ++u) {
        float w = __int_as_float(m[u].y);
        float4 ev = *reinterpret_cast<const float4*>(eb + ((m[u].x & 15) << 9) + slb);
        acc.x = fmaf(w * hv[u].x, ev.x, acc.x);
        acc.y = fmaf(w * hv[u].y, ev.y, acc.y);
        acc.z = fmaf(w * hv[u].z, ev.z, acc.z);
        acc.w = fmaf(w * hv[u].w, ev.w, acc.w);
      }
    }
    if (deg & 7) {                        // one masked tail step
      int2 m[UN];
#pragma unroll
      for (int u = 0; u < UN; ++u) {
        int ep = p + 2 * u + half;
        m[u] = (ep < e) ? emeta[ep] : make_int2(0, 0);  // w=+0 -> adds 0
      }
      float4 hv[UN];
#pragma unroll
      for (int u = 0; u < UN; ++u) {
        if constexpr (L0) {
          int xi = xv[m[u].x >> 9];
          hv[u] = *(reinterpret_cast<const float4*>(atom_emb + (size_t)xi * EMB) + sl);
        } else {
          hv[u] = *reinterpret_cast<const float4*>(hb + (m[u].x & 0xFFFFFE00u) + slb);
        }
      }
#pragma unroll
      for (int u = 0; u < UN; ++u) {
        float w = __int_as_float(m[u].y);
        float4 ev = *reinterpret_cast<const float4*>(eb + ((m[u].x & 15) << 9) + slb);
        acc.x = fmaf(w * hv[u].x, ev.x, acc.x);
        acc.y = fmaf(w * hv[u].y, ev.y, acc.y);
        acc.z = fmaf(w * hv[u].z, ev.z, acc.z);
        acc.w = fmaf(w * hv[u].w, ev.w, acc.w);
      }
    }
  }

  acc.x += __shfl_xor(acc.x, 32);
  acc.y += __shfl_xor(acc.y, 32);
  acc.z += __shfl_xor(acc.z, 32);
  acc.w += __shfl_xor(acc.w, 32);

  if (half == 0) {
    unsigned short h0 = f2bf(acc.x), h1 = f2bf(acc.y);
    unsigned short h2 = f2bf(acc.z), h3 = f2bf(acc.w);
    ushort4 hi4; hi4.x = h0; hi4.y = h1; hi4.z = h2; hi4.w = h3;
    ushort4 lo4;
    lo4.x = f2bf(acc.x - bf2f(h0));
    lo4.y = f2bf(acc.y - bf2f(h1));
    lo4.z = f2bf(acc.z - bf2f(h2));
    lo4.w = f2bf(acc.w - bf2f(h3));
    *(reinterpret_cast<ushort4*>(Ahi + (size_t)node * EMB) + sl) = hi4;
    *(reinterpret_cast<ushort4*>(Alo + (size_t)node * EMB) + sl) = lo4;
  }
}

// ---------- h_next = relu(split_bf16(agg) @ W + b) via MFMA ----------
// PROBE=1: 4x replay (blockIdx % gb), for per-dispatch timing visibility.
template<int PROBE>
__global__ __launch_bounds__(256) void k_gemm(const unsigned short* __restrict__ Ahi,
    const unsigned short* __restrict__ Alo, const unsigned short* __restrict__ Wt,
    const float* __restrict__ bias, float* __restrict__ outp, int M, int gb) {
  int bid = blockIdx.x;
  if constexpr (PROBE) bid = bid % gb;
  int wave = threadIdx.x >> 6, lane = threadIdx.x & 63;
  int lr = lane & 15, lg = lane >> 4;
  int rowbase = bid * 128 + wave * 32;
  f32x4 acc[2][8];
#pragma unroll
  for (int m = 0; m < 2; ++m)
#pragma unroll
    for (int n = 0; n < 8; ++n) acc[m][n] = (f32x4){0.f, 0.f, 0.f, 0.f};

#pragma unroll
  for (int kb = 0; kb < 4; ++kb) {
    int koff = kb * 32 + lg * 8;
    bf16x8 ah[2], al[2];
#pragma unroll
    for (int m = 0; m < 2; ++m) {
      int r = rowbase + m * 16 + lr;
      if (r >= M) r = M - 1;                 // clamp; stores are guarded
      ah[m] = *reinterpret_cast<const bf16x8*>(Ahi + (size_t)r * EMB + koff);
      al[m] = *reinterpret_cast<const bf16x8*>(Alo + (size_t)r * EMB + koff);
    }
#pragma unroll
    for (int n = 0; n < 8; ++n) {
      const unsigned short* wp = Wt + (size_t)(n * 16 + lr) * EMB + koff;
      bf16x8 bh = *reinterpret_cast<const bf16x8*>(wp);
      bf16x8 bl = *reinterpret_cast<const bf16x8*>(wp + 128 * EMB);
#pragma unroll
      for (int m = 0; m < 2; ++m) {
        acc[m][n] = __builtin_amdgcn_mfma_f32_16x16x32_bf16(ah[m], bh, acc[m][n], 0, 0, 0);
        acc[m][n] = __builtin_amdgcn_mfma_f32_16x16x32_bf16(al[m], bh, acc[m][n], 0, 0, 0);
        acc[m][n] = __builtin_amdgcn_mfma_f32_16x16x32_bf16(ah[m], bl, acc[m][n], 0, 0, 0);
      }
    }
  }

#pragma unroll
  for (int n = 0; n < 8; ++n) {
    float bv = bias[n * 16 + lr];
#pragma unroll
    for (int m = 0; m < 2; ++m) {
#pragma unroll
      for (int r4 = 0; r4 < 4; ++r4) {
        int row = rowbase + m * 16 + lg * 4 + r4;
        if (row < M)
          outp[(size_t)row * EMB + n * 16 + lr] = fmaxf(acc[m][n][r4] + bv, 0.f);
      }
    }
  }
}

extern "C" void kernel_launch(void* const* d_in, const int* in_sizes, int n_in,
                              void* d_out, int out_size, void* d_ws, size_t ws_size,
                              hipStream_t stream) {
  const int*   x        = (const int*)d_in[0];
  const int*   eidx     = (const int*)d_in[1];
  const int*   eattr    = (const int*)d_in[2];
  const float* atom_emb = (const float*)d_in[3];
  const float* bond_emb = (const float*)d_in[4];
  const float* lin_W    = (const float*)d_in[5];
  const float* lin_b    = (const float*)d_in[6];
  float* out = (float*)d_out;

  const int N = in_sizes[0];
  const int E = in_sizes[1] / 2;
  const int L = in_sizes[5] / (EMB * EMB);
  const int BV = in_sizes[4] / EMB;
  const int* row = eidx;
  const int* col = eidx + E;

  const int NS = (E + (1 << HSTRIPE_LOG) - 1) >> HSTRIPE_LOG;
  const int NR = (N + HRANGE - 1) / HRANGE;

  char* ws = (char*)d_ws;
  size_t off = 0;
  auto alloc = [&](size_t bytes) {
    char* p = ws + off;
    off += (bytes + 255) & ~(size_t)255;
    return p;
  };
  float*          hbuf    = (float*)alloc((size_t)N * EMB * 4);
  unsigned short* Ahi     = (unsigned short*)alloc((size_t)N * EMB * 2);
  unsigned short* Alo     = (unsigned short*)alloc((size_t)N * EMB * 2);
  unsigned short* Wt      = (unsigned short*)alloc((size_t)L * 256 * EMB * 2);
  unsigned short* degP    = (unsigned short*)alloc((size_t)NS * N * 2);
  unsigned short* cntP    = (unsigned short*)alloc((size_t)NS * N * 2);
  int*            cnt     = (int*)alloc((size_t)N * 4);
  int*            startp  = (int*)alloc((size_t)(N + 1) * 4);
  float*          dinv    = (float*)alloc((size_t)N * 4);
  int*            partial = (int*)alloc((size_t)1024 * 4);
  int*            ord     = (int*)alloc((size_t)E * 4);
  int2*           emeta   = (int2*)alloc((size_t)E * 8);
  (void)ws_size; (void)n_in; (void)out_size;

  int eb = (E + 255) / 256;
  int nb = (N + 255) / 256;
  dim3 hgrid(NS, NR);
  k_hist<<<hgrid, 256, 0, stream>>>(row, col, degP, cntP, ord, E, N);
  k_dinv<<<nb, 256, 0, stream>>>(degP, dinv, N, NS);
  k_colreduce<<<nb, 256, 0, stream>>>(cntP, cnt, N, NS);
  k_scan_local<<<nb, 256, 0, stream>>>(cnt, startp, partial, N);
  k_scan_part<<<1, 1024, 0, stream>>>(partial, nb);
  k_scan_add<<<nb, 256, 0, stream>>>(startp, partial, N, E);
  k_fill<<<eb, 256, 0, stream>>>(row, col, eattr, startp, cntP, ord, dinv, emeta, E, N);
  int wtot = L * EMB * EMB;
  k_wsplit<<<(wtot + 255) / 256, 256, 0, stream>>>(lin_W, Wt, wtot);

  int ab = (N + 3) / 4;
  int gb = (N + 127) / 128;
  float* hcur = hbuf;
  for (int l = 0; l < L; ++l) {
    if (l == 0)
      k_agg<1, 0><<<ab, 256, 0, stream>>>(hcur, x, atom_emb, startp, emeta, bond_emb,
                                          Ahi, Alo, N, BV);
    else
      k_agg<0, 0><<<ab, 256, 0, stream>>>(hcur, x, atom_emb, startp, emeta, bond_emb,
                                          Ahi, Alo, N, BV);
    float* hnext = (l == L - 1) ? out : ((hcur == hbuf) ? out : hbuf);
    k_gemm<0><<<gb, 256, 0, stream>>>(Ahi, Alo, Wt + (size_t)l * 256 * EMB,
                                      lin_b + (size_t)l * EMB, hnext, N, gb);
    hcur = hnext;
  }

  // ---- diagnostic probes (write only dead scratch; d_out untouched) ----
  // P2: gather-only agg, 2x amplified -> isolates pure gather throughput
  k_agg<0, 2><<<ab * 2, 256, 0, stream>>>(hbuf, x, atom_emb, startp, emeta,
                                          bond_emb, Ahi, Alo, N, BV);
  // P3: gemm 4x amplified -> reveals true per-gemm time (hidden below top-5 cutoff)
  k_gemm<1><<<gb * 4, 256, 0, stream>>>(Ahi, Alo, Wt, lin_b, hbuf, N, gb);
}

// Round 11
// 456.621 us; speedup vs baseline: 1.4211x; 1.4211x over previous
//
#include <hip/hip_runtime.h>

#define EMB 128
#define HRANGE 16384       // nodes per histogram range (64 KB LDS, packed cnt|deg)
#define HSTRIPE_LOG 13     // 8192 edges per stripe
#define UN 4

typedef __attribute__((ext_vector_type(8))) short bf16x8;
typedef __attribute__((ext_vector_type(4))) float f32x4;

__device__ inline unsigned short f2bf(float f) {
  unsigned u = __float_as_uint(f);
  return (unsigned short)((u + 0x7FFF + ((u >> 16) & 1)) >> 16);   // RNE
}
__device__ inline float bf2f(unsigned short s) {
  return __uint_as_float(((unsigned)s) << 16);
}

// ---------- CSR build via LDS histograms, packed cnt|deg (no global atomics) ----
__global__ __launch_bounds__(256) void k_hist(const int* __restrict__ row,
    const int* __restrict__ col, unsigned short* __restrict__ degP,
    unsigned short* __restrict__ cntP, int* __restrict__ ord, int E, int N) {
  __shared__ unsigned int hw[HRANGE];
  int s = blockIdx.x, r = blockIdx.y;
  int nlo = r * HRANGE;
  for (int t = threadIdx.x; t < HRANGE; t += 256) hw[t] = 0u;
  __syncthreads();
  int k0 = s << HSTRIPE_LOG;
  int k1 = min(E, k0 + (1 << HSTRIPE_LOG));
  for (int k = k0 + threadIdx.x; k < k1; k += 256) {
    int c = col[k] - nlo;
    if ((unsigned)c < HRANGE)
      ord[k] = (int)(atomicAdd(&hw[c], 1u) & 0xFFFFu);
    int rr = row[k] - nlo;
    if ((unsigned)rr < HRANGE)
      atomicAdd(&hw[rr], 0x10000u);
  }
  __syncthreads();
  for (int t = threadIdx.x; t < HRANGE; t += 256) {
    int node = nlo + t;
    if (node < N) {
      unsigned w = hw[t];
      cntP[(size_t)s * N + node] = (unsigned short)(w & 0xFFFFu);
      degP[(size_t)s * N + node] = (unsigned short)(w >> 16);
    }
  }
}

// fused: exclusive prefix of cnt over stripes (in place) + total cnt + dinv
__global__ __launch_bounds__(256) void k_cdr(unsigned short* __restrict__ cntP,
    const unsigned short* __restrict__ degP, int* __restrict__ cnt,
    float* __restrict__ dinv, int N, int ns) {
  int i = blockIdx.x * 256 + threadIdx.x;
  if (i < N) {
    int ssum = 0, d = 0;
    for (int s = 0; s < ns; ++s) {
      int v = cntP[(size_t)s * N + i];
      cntP[(size_t)s * N + i] = (unsigned short)ssum;
      ssum += v;
      d += degP[(size_t)s * N + i];
    }
    cnt[i] = ssum;
    float df = (float)(d == 0 ? 1 : d);
    dinv[i] = 1.0f / sqrtf(df);
  }
}

// ---------- multi-block exclusive scan ----------
__global__ __launch_bounds__(256) void k_scan_local(const int* __restrict__ cnt,
    int* __restrict__ startp, int* __restrict__ partial, int N) {
  __shared__ int lds[256];
  int tid = threadIdx.x;
  int i = blockIdx.x * 256 + tid;
  int v = (i < N) ? cnt[i] : 0;
  lds[tid] = v;
  __syncthreads();
#pragma unroll
  for (int off = 1; off < 256; off <<= 1) {
    int t = (tid >= off) ? lds[tid - off] : 0;
    __syncthreads();
    lds[tid] += t;
    __syncthreads();
  }
  if (i < N) startp[i] = lds[tid] - v;
  if (tid == 255) partial[blockIdx.x] = lds[255];
}

__global__ void k_scan_part(int* __restrict__ partial, int nb) {
  __shared__ int lds[1024];
  int tid = threadIdx.x;
  int v = (tid < nb) ? partial[tid] : 0;
  lds[tid] = v;
  __syncthreads();
  for (int off = 1; off < 1024; off <<= 1) {
    int t = (tid >= off) ? lds[tid - off] : 0;
    __syncthreads();
    lds[tid] += t;
    __syncthreads();
  }
  if (tid < nb) partial[tid] = lds[tid] - v;
}

__global__ __launch_bounds__(256) void k_scan_add(int* __restrict__ startp,
    const int* __restrict__ partial, int N, int E) {
  int i = blockIdx.x * 256 + threadIdx.x;
  if (i < N) startp[i] += partial[blockIdx.x];
  if (i == 0) startp[N] = E;
}

// emeta pack: m.x = (src<<9) | bond  (src*512 = h-row byte offset; bond in low 4)
__global__ __launch_bounds__(256) void k_fill(const int* __restrict__ row,
    const int* __restrict__ col, const int* __restrict__ attr,
    const int* __restrict__ startp, const unsigned short* __restrict__ cntP,
    const int* __restrict__ ord, const float* __restrict__ dinv,
    int2* __restrict__ emeta, int E, int N) {
  int k = blockIdx.x * 256 + threadIdx.x;
  if (k < E) {
    int r = row[k], c = col[k];
    int s = k >> HSTRIPE_LOG;
    int pos = startp[c] + (int)cntP[(size_t)s * N + c] + ord[k];
    int2 m;
    m.x = (r << 9) | attr[k];
    m.y = __float_as_int(dinv[r] * dinv[c]);
    emeta[pos] = m;
  }
}

// ---------- W split: Wt[l][ 0..127 ][k]=hi, Wt[l][128..255][k]=lo (col-major) ----
__global__ __launch_bounds__(256) void k_wsplit(const float* __restrict__ W,
    unsigned short* __restrict__ Wt, int total) {
  int t = blockIdx.x * 256 + threadIdx.x;   // t = (l*128 + k)*128 + n
  if (t >= total) return;
  int n = t & 127, k = (t >> 7) & 127, l = t >> 14;
  float v = W[t];
  unsigned short hi = f2bf(v);
  unsigned short lo = f2bf(v - bf2f(hi));
  size_t base = (size_t)l * 256 * EMB;
  Wt[base + (size_t)n * EMB + k] = hi;
  Wt[base + (size_t)(128 + n) * EMB + k] = lo;
}

// ---------- aggregation: one wave per node, half-wave per edge (full 512B row),
// 8 edges/iter in flight. At the per-XCD fabric-read roofline (r10 probe). ----
template<int L0>
__global__ __launch_bounds__(256) void k_agg(const float* __restrict__ h,
    const int* __restrict__ xv, const float* __restrict__ atom_emb,
    const int* __restrict__ startp, const int2* __restrict__ emeta,
    const float* __restrict__ bond_emb, unsigned short* __restrict__ Ahi,
    unsigned short* __restrict__ Alo, int N, int BV) {
  __shared__ float eb_lds[16 * EMB];           // bond table, 8 KB
  for (int t = threadIdx.x; t < BV * (EMB / 4); t += 256)
    reinterpret_cast<float4*>(eb_lds)[t] =
        reinterpret_cast<const float4*>(bond_emb)[t];
  __syncthreads();

  int wave = threadIdx.x >> 6, lane = threadIdx.x & 63;
  int half = lane >> 5, sl = lane & 31;
  int node = blockIdx.x * 4 + wave;
  if (node >= N) return;
  int s = startp[node], e = startp[node + 1];
  int deg = e - s;
  float4 acc = make_float4(0.f, 0.f, 0.f, 0.f);
  const char* hb = (const char*)h;
  const char* eb = (const char*)eb_lds;
  int slb = sl << 4;

  int nfull = deg >> 3;                 // unchecked 8-edge iterations
  int p = s;
  for (int it = 0; it < nfull; ++it, p += 8) {
    int2 m[UN];
#pragma unroll
    for (int u = 0; u < UN; ++u) m[u] = emeta[p + 2 * u + half];
    float4 hv[UN];
#pragma unroll
    for (int u = 0; u < UN; ++u) {
      if constexpr (L0) {
        int xi = xv[m[u].x >> 9];
        hv[u] = *(reinterpret_cast<const float4*>(atom_emb + (size_t)xi * EMB) + sl);
      } else {
        hv[u] = *reinterpret_cast<const float4*>(hb + (m[u].x & 0xFFFFFE00u) + slb);
      }
    }
#pragma unroll
    for (int u = 0; u < UN; ++u) {
      float w = __int_as_float(m[u].y);
      float4 ev = *reinterpret_cast<const float4*>(eb + ((m[u].x & 15) << 9) + slb);
      acc.x = fmaf(w * hv[u].x, ev.x, acc.x);
      acc.y = fmaf(w * hv[u].y, ev.y, acc.y);
      acc.z = fmaf(w * hv[u].z, ev.z, acc.z);
      acc.w = fmaf(w * hv[u].w, ev.w, acc.w);
    }
  }
  if (deg & 7) {                        // one masked tail step
    int2 m[UN];
#pragma unroll
    for (int u = 0; u < UN; ++u) {
      int ep = p + 2 * u + half;
      m[u] = (ep < e) ? emeta[ep] : make_int2(0, 0);  // w=+0 -> adds 0
    }
    float4 hv[UN];
#pragma unroll
    for (int u = 0; u < UN; ++u) {
      if constexpr (L0) {
        int xi = xv[m[u].x >> 9];
        hv[u] = *(reinterpret_cast<const float4*>(atom_emb + (size_t)xi * EMB) + sl);
      } else {
        hv[u] = *reinterpret_cast<const float4*>(hb + (m[u].x & 0xFFFFFE00u) + slb);
      }
    }
#pragma unroll
    for (int u = 0; u < UN; ++u) {
      float w = __int_as_float(m[u].y);
      float4 ev = *reinterpret_cast<const float4*>(eb + ((m[u].x & 15) << 9) + slb);
      acc.x = fmaf(w * hv[u].x, ev.x, acc.x);
      acc.y = fmaf(w * hv[u].y, ev.y, acc.y);
      acc.z = fmaf(w * hv[u].z, ev.z, acc.z);
      acc.w = fmaf(w * hv[u].w, ev.w, acc.w);
    }
  }

  acc.x += __shfl_xor(acc.x, 32);
  acc.y += __shfl_xor(acc.y, 32);
  acc.z += __shfl_xor(acc.z, 32);
  acc.w += __shfl_xor(acc.w, 32);

  if (half == 0) {
    unsigned short h0 = f2bf(acc.x), h1 = f2bf(acc.y);
    unsigned short h2 = f2bf(acc.z), h3 = f2bf(acc.w);
    ushort4 hi4; hi4.x = h0; hi4.y = h1; hi4.z = h2; hi4.w = h3;
    ushort4 lo4;
    lo4.x = f2bf(acc.x - bf2f(h0));
    lo4.y = f2bf(acc.y - bf2f(h1));
    lo4.z = f2bf(acc.z - bf2f(h2));
    lo4.w = f2bf(acc.w - bf2f(h3));
    *(reinterpret_cast<ushort4*>(Ahi + (size_t)node * EMB) + sl) = hi4;
    *(reinterpret_cast<ushort4*>(Alo + (size_t)node * EMB) + sl) = lo4;
  }
}

// ---------- h_next = relu(split_bf16(agg) @ W + b) via MFMA ----------
// 64 rows/block (782 blocks): 2x memory-parallelism vs 128-row version
// (r10 P3 probe: 19 us at 391 blocks = grid-starved, 19% wave occupancy).
__global__ __launch_bounds__(256) void k_gemm(const unsigned short* __restrict__ Ahi,
    const unsigned short* __restrict__ Alo, const unsigned short* __restrict__ Wt,
    const float* __restrict__ bias, float* __restrict__ outp, int M) {
  int wave = threadIdx.x >> 6, lane = threadIdx.x & 63;
  int lr = lane & 15, lg = lane >> 4;
  int rowbase = blockIdx.x * 64 + wave * 16;
  f32x4 acc[8];
#pragma unroll
  for (int n = 0; n < 8; ++n) acc[n] = (f32x4){0.f, 0.f, 0.f, 0.f};

#pragma unroll
  for (int kb = 0; kb < 4; ++kb) {
    int koff = kb * 32 + lg * 8;
    int r = rowbase + lr;
    if (r >= M) r = M - 1;                 // clamp; stores are guarded
    bf16x8 ah = *reinterpret_cast<const bf16x8*>(Ahi + (size_t)r * EMB + koff);
    bf16x8 al = *reinterpret_cast<const bf16x8*>(Alo + (size_t)r * EMB + koff);
#pragma unroll
    for (int n = 0; n < 8; ++n) {
      const unsigned short* wp = Wt + (size_t)(n * 16 + lr) * EMB + koff;
      bf16x8 bh = *reinterpret_cast<const bf16x8*>(wp);
      bf16x8 bl = *reinterpret_cast<const bf16x8*>(wp + 128 * EMB);
      acc[n] = __builtin_amdgcn_mfma_f32_16x16x32_bf16(ah, bh, acc[n], 0, 0, 0);
      acc[n] = __builtin_amdgcn_mfma_f32_16x16x32_bf16(al, bh, acc[n], 0, 0, 0);
      acc[n] = __builtin_amdgcn_mfma_f32_16x16x32_bf16(ah, bl, acc[n], 0, 0, 0);
    }
  }

#pragma unroll
  for (int n = 0; n < 8; ++n) {
    float bv = bias[n * 16 + lr];
#pragma unroll
    for (int r4 = 0; r4 < 4; ++r4) {
      int row = rowbase + lg * 4 + r4;
      if (row < M)
        outp[(size_t)row * EMB + n * 16 + lr] = fmaxf(acc[n][r4] + bv, 0.f);
    }
  }
}

extern "C" void kernel_launch(void* const* d_in, const int* in_sizes, int n_in,
                              void* d_out, int out_size, void* d_ws, size_t ws_size,
                              hipStream_t stream) {
  const int*   x        = (const int*)d_in[0];
  const int*   eidx     = (const int*)d_in[1];
  const int*   eattr    = (const int*)d_in[2];
  const float* atom_emb = (const float*)d_in[3];
  const float* bond_emb = (const float*)d_in[4];
  const float* lin_W    = (const float*)d_in[5];
  const float* lin_b    = (const float*)d_in[6];
  float* out = (float*)d_out;

  const int N = in_sizes[0];
  const int E = in_sizes[1] / 2;
  const int L = in_sizes[5] / (EMB * EMB);
  const int BV = in_sizes[4] / EMB;
  const int* row = eidx;
  const int* col = eidx + E;

  const int NS = (E + (1 << HSTRIPE_LOG) - 1) >> HSTRIPE_LOG;
  const int NR = (N + HRANGE - 1) / HRANGE;

  char* ws = (char*)d_ws;
  size_t off = 0;
  auto alloc = [&](size_t bytes) {
    char* p = ws + off;
    off += (bytes + 255) & ~(size_t)255;
    return p;
  };
  float*          hbuf    = (float*)alloc((size_t)N * EMB * 4);
  unsigned short* Ahi     = (unsigned short*)alloc((size_t)N * EMB * 2);
  unsigned short* Alo     = (unsigned short*)alloc((size_t)N * EMB * 2);
  unsigned short* Wt      = (unsigned short*)alloc((size_t)L * 256 * EMB * 2);
  unsigned short* degP    = (unsigned short*)alloc((size_t)NS * N * 2);
  unsigned short* cntP    = (unsigned short*)alloc((size_t)NS * N * 2);
  int*            cnt     = (int*)alloc((size_t)N * 4);
  int*            startp  = (int*)alloc((size_t)(N + 1) * 4);
  float*          dinv    = (float*)alloc((size_t)N * 4);
  int*            partial = (int*)alloc((size_t)1024 * 4);
  int*            ord     = (int*)alloc((size_t)E * 4);
  int2*           emeta   = (int2*)alloc((size_t)E * 8);
  (void)ws_size; (void)n_in; (void)out_size;

  int eb = (E + 255) / 256;
  int nb = (N + 255) / 256;
  dim3 hgrid(NS, NR);
  k_hist<<<hgrid, 256, 0, stream>>>(row, col, degP, cntP, ord, E, N);
  k_cdr<<<nb, 256, 0, stream>>>(cntP, degP, cnt, dinv, N, NS);
  k_scan_local<<<nb, 256, 0, stream>>>(cnt, startp, partial, N);
  k_scan_part<<<1, 1024, 0, stream>>>(partial, nb);
  k_scan_add<<<nb, 256, 0, stream>>>(startp, partial, N, E);
  k_fill<<<eb, 256, 0, stream>>>(row, col, eattr, startp, cntP, ord, dinv, emeta, E, N);
  int wtot = L * EMB * EMB;
  k_wsplit<<<(wtot + 255) / 256, 256, 0, stream>>>(lin_W, Wt, wtot);

  int ab = (N + 3) / 4;
  int gb = (N + 63) / 64;
  float* hcur = hbuf;
  for (int l = 0; l < L; ++l) {
    if (l == 0)
      k_agg<1><<<ab, 256, 0, stream>>>(hcur, x, atom_emb, startp, emeta, bond_emb,
                                       Ahi, Alo, N, BV);
    else
      k_agg<0><<<ab, 256, 0, stream>>>(hcur, x, atom_emb, startp, emeta, bond_emb,
                                       Ahi, Alo, N, BV);
    float* hnext = (l == L - 1) ? out : ((hcur == hbuf) ? out : hbuf);
    k_gemm<<<gb, 256, 0, stream>>>(Ahi, Alo, Wt + (size_t)l * 256 * EMB,
                                   lin_b + (size_t)l * EMB, hnext, N);
    hcur = hnext;
  }
}

// Round 12
// 416.781 us; speedup vs baseline: 1.5570x; 1.0956x over previous
//
#include <hip/hip_runtime.h>

#define EMB 128
#define HRANGE 16384       // nodes per histogram range (64 KB LDS, packed cnt|deg)
#define HSTRIPE_LOG 13     // 8192 edges per stripe
#define UN 4

typedef __attribute__((ext_vector_type(8))) short bf16x8;
typedef __attribute__((ext_vector_type(4))) float f32x4;

__device__ inline unsigned short f2bf(float f) {
  unsigned u = __float_as_uint(f);
  return (unsigned short)((u + 0x7FFF + ((u >> 16) & 1)) >> 16);   // RNE
}
__device__ inline float bf2f(unsigned short s) {
  return __uint_as_float(((unsigned)s) << 16);
}

// ---------- CSR build via LDS histograms, packed cnt|deg (no global atomics) ----
__global__ __launch_bounds__(256) void k_hist(const int* __restrict__ row,
    const int* __restrict__ col, unsigned short* __restrict__ degP,
    unsigned short* __restrict__ cntP, int* __restrict__ ord, int E, int N) {
  __shared__ unsigned int hw[HRANGE];
  int s = blockIdx.x, r = blockIdx.y;
  int nlo = r * HRANGE;
  for (int t = threadIdx.x; t < HRANGE; t += 256) hw[t] = 0u;
  __syncthreads();
  int k0 = s << HSTRIPE_LOG;
  int k1 = min(E, k0 + (1 << HSTRIPE_LOG));
  for (int k = k0 + threadIdx.x; k < k1; k += 256) {
    int c = col[k] - nlo;
    if ((unsigned)c < HRANGE)
      ord[k] = (int)(atomicAdd(&hw[c], 1u) & 0xFFFFu);
    int rr = row[k] - nlo;
    if ((unsigned)rr < HRANGE)
      atomicAdd(&hw[rr], 0x10000u);
  }
  __syncthreads();
  for (int t = threadIdx.x; t < HRANGE; t += 256) {
    int node = nlo + t;
    if (node < N) {
      unsigned w = hw[t];
      cntP[(size_t)s * N + node] = (unsigned short)(w & 0xFFFFu);
      degP[(size_t)s * N + node] = (unsigned short)(w >> 16);
    }
  }
}

// fused: exclusive prefix of cnt over stripes (in place) + total cnt + dinv
__global__ __launch_bounds__(256) void k_cdr(unsigned short* __restrict__ cntP,
    const unsigned short* __restrict__ degP, int* __restrict__ cnt,
    float* __restrict__ dinv, int N, int ns) {
  int i = blockIdx.x * 256 + threadIdx.x;
  if (i < N) {
    int ssum = 0, d = 0;
    for (int s = 0; s < ns; ++s) {
      int v = cntP[(size_t)s * N + i];
      cntP[(size_t)s * N + i] = (unsigned short)ssum;
      ssum += v;
      d += degP[(size_t)s * N + i];
    }
    cnt[i] = ssum;
    float df = (float)(d == 0 ? 1 : d);
    dinv[i] = 1.0f / sqrtf(df);
  }
}

// ---------- multi-block exclusive scan ----------
__global__ __launch_bounds__(256) void k_scan_local(const int* __restrict__ cnt,
    int* __restrict__ startp, int* __restrict__ partial, int N) {
  __shared__ int lds[256];
  int tid = threadIdx.x;
  int i = blockIdx.x * 256 + tid;
  int v = (i < N) ? cnt[i] : 0;
  lds[tid] = v;
  __syncthreads();
#pragma unroll
  for (int off = 1; off < 256; off <<= 1) {
    int t = (tid >= off) ? lds[tid - off] : 0;
    __syncthreads();
    lds[tid] += t;
    __syncthreads();
  }
  if (i < N) startp[i] = lds[tid] - v;
  if (tid == 255) partial[blockIdx.x] = lds[255];
}

__global__ void k_scan_part(int* __restrict__ partial, int nb) {
  __shared__ int lds[1024];
  int tid = threadIdx.x;
  int v = (tid < nb) ? partial[tid] : 0;
  lds[tid] = v;
  __syncthreads();
  for (int off = 1; off < 1024; off <<= 1) {
    int t = (tid >= off) ? lds[tid - off] : 0;
    __syncthreads();
    lds[tid] += t;
    __syncthreads();
  }
  if (tid < nb) partial[tid] = lds[tid] - v;
}

__global__ __launch_bounds__(256) void k_scan_add(int* __restrict__ startp,
    const int* __restrict__ partial, int N, int E) {
  int i = blockIdx.x * 256 + threadIdx.x;
  if (i < N) startp[i] += partial[blockIdx.x];
  if (i == 0) startp[N] = E;
}

// emeta pack: m.x = (src<<9) | bond  (src*512 = h-row byte offset; bond in low 4)
__global__ __launch_bounds__(256) void k_fill(const int* __restrict__ row,
    const int* __restrict__ col, const int* __restrict__ attr,
    const int* __restrict__ startp, const unsigned short* __restrict__ cntP,
    const int* __restrict__ ord, const float* __restrict__ dinv,
    int2* __restrict__ emeta, int E, int N) {
  int k = blockIdx.x * 256 + threadIdx.x;
  if (k < E) {
    int r = row[k], c = col[k];
    int s = k >> HSTRIPE_LOG;
    int pos = startp[c] + (int)cntP[(size_t)s * N + c] + ord[k];
    int2 m;
    m.x = (r << 9) | attr[k];
    m.y = __float_as_int(dinv[r] * dinv[c]);
    emeta[pos] = m;
  }
}

// ---------- W split: Wt[l][ 0..127 ][k]=hi, Wt[l][128..255][k]=lo (col-major) ----
__global__ __launch_bounds__(256) void k_wsplit(const float* __restrict__ W,
    unsigned short* __restrict__ Wt, int total) {
  int t = blockIdx.x * 256 + threadIdx.x;   // t = (l*128 + k)*128 + n
  if (t >= total) return;
  int n = t & 127, k = (t >> 7) & 127, l = t >> 14;
  float v = W[t];
  unsigned short hi = f2bf(v);
  unsigned short lo = f2bf(v - bf2f(hi));
  size_t base = (size_t)l * 256 * EMB;
  Wt[base + (size_t)n * EMB + k] = hi;
  Wt[base + (size_t)(128 + n) * EMB + k] = lo;
}

// ---------- aggregation: one wave per node, half-wave per edge (full 512B row),
// 8 edges/iter in flight. At the measured gather-path roofline (r10 probe:
// gather-only == full kernel; 176MB FETCH @ ~3.2 TB/s fabric read). ----
template<int L0>
__global__ __launch_bounds__(256) void k_agg(const float* __restrict__ h,
    const int* __restrict__ xv, const float* __restrict__ atom_emb,
    const int* __restrict__ startp, const int2* __restrict__ emeta,
    const float* __restrict__ bond_emb, unsigned short* __restrict__ Ahi,
    unsigned short* __restrict__ Alo, int N, int BV) {
  __shared__ float eb_lds[16 * EMB];           // bond table, 8 KB
  for (int t = threadIdx.x; t < BV * (EMB / 4); t += 256)
    reinterpret_cast<float4*>(eb_lds)[t] =
        reinterpret_cast<const float4*>(bond_emb)[t];
  __syncthreads();

  int wave = threadIdx.x >> 6, lane = threadIdx.x & 63;
  int half = lane >> 5, sl = lane & 31;
  int node = blockIdx.x * 4 + wave;
  if (node >= N) return;
  int s = startp[node], e = startp[node + 1];
  int deg = e - s;
  float4 acc = make_float4(0.f, 0.f, 0.f, 0.f);
  const char* hb = (const char*)h;
  const char* eb = (const char*)eb_lds;
  int slb = sl << 4;

  int nfull = deg >> 3;                 // unchecked 8-edge iterations
  int p = s;
  for (int it = 0; it < nfull; ++it, p += 8) {
    int2 m[UN];
#pragma unroll
    for (int u = 0; u < UN; ++u) m[u] = emeta[p + 2 * u + half];
    float4 hv[UN];
#pragma unroll
    for (int u = 0; u < UN; ++u) {
      if constexpr (L0) {
        int xi = xv[m[u].x >> 9];
        hv[u] = *(reinterpret_cast<const float4*>(atom_emb + (size_t)xi * EMB) + sl);
      } else {
        hv[u] = *reinterpret_cast<const float4*>(hb + (m[u].x & 0xFFFFFE00u) + slb);
      }
    }
#pragma unroll
    for (int u = 0; u < UN; ++u) {
      float w = __int_as_float(m[u].y);
      float4 ev = *reinterpret_cast<const float4*>(eb + ((m[u].x & 15) << 9) + slb);
      acc.x = fmaf(w * hv[u].x, ev.x, acc.x);
      acc.y = fmaf(w * hv[u].y, ev.y, acc.y);
      acc.z = fmaf(w * hv[u].z, ev.z, acc.z);
      acc.w = fmaf(w * hv[u].w, ev.w, acc.w);
    }
  }
  if (deg & 7) {                        // one masked tail step
    int2 m[UN];
#pragma unroll
    for (int u = 0; u < UN; ++u) {
      int ep = p + 2 * u + half;
      m[u] = (ep < e) ? emeta[ep] : make_int2(0, 0);  // w=+0 -> adds 0
    }
    float4 hv[UN];
#pragma unroll
    for (int u = 0; u < UN; ++u) {
      if constexpr (L0) {
        int xi = xv[m[u].x >> 9];
        hv[u] = *(reinterpret_cast<const float4*>(atom_emb + (size_t)xi * EMB) + sl);
      } else {
        hv[u] = *reinterpret_cast<const float4*>(hb + (m[u].x & 0xFFFFFE00u) + slb);
      }
    }
#pragma unroll
    for (int u = 0; u < UN; ++u) {
      float w = __int_as_float(m[u].y);
      float4 ev = *reinterpret_cast<const float4*>(eb + ((m[u].x & 15) << 9) + slb);
      acc.x = fmaf(w * hv[u].x, ev.x, acc.x);
      acc.y = fmaf(w * hv[u].y, ev.y, acc.y);
      acc.z = fmaf(w * hv[u].z, ev.z, acc.z);
      acc.w = fmaf(w * hv[u].w, ev.w, acc.w);
    }
  }

  acc.x += __shfl_xor(acc.x, 32);
  acc.y += __shfl_xor(acc.y, 32);
  acc.z += __shfl_xor(acc.z, 32);
  acc.w += __shfl_xor(acc.w, 32);

  if (half == 0) {
    unsigned short h0 = f2bf(acc.x), h1 = f2bf(acc.y);
    unsigned short h2 = f2bf(acc.z), h3 = f2bf(acc.w);
    ushort4 hi4; hi4.x = h0; hi4.y = h1; hi4.z = h2; hi4.w = h3;
    ushort4 lo4;
    lo4.x = f2bf(acc.x - bf2f(h0));
    lo4.y = f2bf(acc.y - bf2f(h1));
    lo4.z = f2bf(acc.z - bf2f(h2));
    lo4.w = f2bf(acc.w - bf2f(h3));
    *(reinterpret_cast<ushort4*>(Ahi + (size_t)node * EMB) + sl) = hi4;
    *(reinterpret_cast<ushort4*>(Alo + (size_t)node * EMB) + sl) = lo4;
  }
}

// ---------- h_next = relu(split_bf16(agg) @ W + b) via MFMA ----------
// 128 rows/block, 4 waves, 32 rows/wave — r9 shape, measured ~19us (r10 P3).
// 64-row variant regressed (+20us: 2x per-row W traffic, r11 lesson).
__global__ __launch_bounds__(256) void k_gemm(const unsigned short* __restrict__ Ahi,
    const unsigned short* __restrict__ Alo, const unsigned short* __restrict__ Wt,
    const float* __restrict__ bias, float* __restrict__ outp, int M) {
  int wave = threadIdx.x >> 6, lane = threadIdx.x & 63;
  int lr = lane & 15, lg = lane >> 4;
  int rowbase = blockIdx.x * 128 + wave * 32;
  f32x4 acc[2][8];
#pragma unroll
  for (int m = 0; m < 2; ++m)
#pragma unroll
    for (int n = 0; n < 8; ++n) acc[m][n] = (f32x4){0.f, 0.f, 0.f, 0.f};

#pragma unroll
  for (int kb = 0; kb < 4; ++kb) {
    int koff = kb * 32 + lg * 8;
    bf16x8 ah[2], al[2];
#pragma unroll
    for (int m = 0; m < 2; ++m) {
      int r = rowbase + m * 16 + lr;
      if (r >= M) r = M - 1;                 // clamp; stores are guarded
      ah[m] = *reinterpret_cast<const bf16x8*>(Ahi + (size_t)r * EMB + koff);
      al[m] = *reinterpret_cast<const bf16x8*>(Alo + (size_t)r * EMB + koff);
    }
#pragma unroll
    for (int n = 0; n < 8; ++n) {
      const unsigned short* wp = Wt + (size_t)(n * 16 + lr) * EMB + koff;
      bf16x8 bh = *reinterpret_cast<const bf16x8*>(wp);
      bf16x8 bl = *reinterpret_cast<const bf16x8*>(wp + 128 * EMB);
#pragma unroll
      for (int m = 0; m < 2; ++m) {
        acc[m][n] = __builtin_amdgcn_mfma_f32_16x16x32_bf16(ah[m], bh, acc[m][n], 0, 0, 0);
        acc[m][n] = __builtin_amdgcn_mfma_f32_16x16x32_bf16(al[m], bh, acc[m][n], 0, 0, 0);
        acc[m][n] = __builtin_amdgcn_mfma_f32_16x16x32_bf16(ah[m], bl, acc[m][n], 0, 0, 0);
      }
    }
  }

#pragma unroll
  for (int n = 0; n < 8; ++n) {
    float bv = bias[n * 16 + lr];
#pragma unroll
    for (int m = 0; m < 2; ++m) {
#pragma unroll
      for (int r4 = 0; r4 < 4; ++r4) {
        int row = rowbase + m * 16 + lg * 4 + r4;
        if (row < M)
          outp[(size_t)row * EMB + n * 16 + lr] = fmaxf(acc[m][n][r4] + bv, 0.f);
      }
    }
  }
}

extern "C" void kernel_launch(void* const* d_in, const int* in_sizes, int n_in,
                              void* d_out, int out_size, void* d_ws, size_t ws_size,
                              hipStream_t stream) {
  const int*   x        = (const int*)d_in[0];
  const int*   eidx     = (const int*)d_in[1];
  const int*   eattr    = (const int*)d_in[2];
  const float* atom_emb = (const float*)d_in[3];
  const float* bond_emb = (const float*)d_in[4];
  const float* lin_W    = (const float*)d_in[5];
  const float* lin_b    = (const float*)d_in[6];
  float* out = (float*)d_out;

  const int N = in_sizes[0];
  const int E = in_sizes[1] / 2;
  const int L = in_sizes[5] / (EMB * EMB);
  const int BV = in_sizes[4] / EMB;
  const int* row = eidx;
  const int* col = eidx + E;

  const int NS = (E + (1 << HSTRIPE_LOG) - 1) >> HSTRIPE_LOG;
  const int NR = (N + HRANGE - 1) / HRANGE;

  char* ws = (char*)d_ws;
  size_t off = 0;
  auto alloc = [&](size_t bytes) {
    char* p = ws + off;
    off += (bytes + 255) & ~(size_t)255;
    return p;
  };
  float*          hbuf    = (float*)alloc((size_t)N * EMB * 4);
  unsigned short* Ahi     = (unsigned short*)alloc((size_t)N * EMB * 2);
  unsigned short* Alo     = (unsigned short*)alloc((size_t)N * EMB * 2);
  unsigned short* Wt      = (unsigned short*)alloc((size_t)L * 256 * EMB * 2);
  unsigned short* degP    = (unsigned short*)alloc((size_t)NS * N * 2);
  unsigned short* cntP    = (unsigned short*)alloc((size_t)NS * N * 2);
  int*            cnt     = (int*)alloc((size_t)N * 4);
  int*            startp  = (int*)alloc((size_t)(N + 1) * 4);
  float*          dinv    = (float*)alloc((size_t)N * 4);
  int*            partial = (int*)alloc((size_t)1024 * 4);
  int*            ord     = (int*)alloc((size_t)E * 4);
  int2*           emeta   = (int2*)alloc((size_t)E * 8);
  (void)ws_size; (void)n_in; (void)out_size;

  int eb = (E + 255) / 256;
  int nb = (N + 255) / 256;
  dim3 hgrid(NS, NR);
  k_hist<<<hgrid, 256, 0, stream>>>(row, col, degP, cntP, ord, E, N);
  k_cdr<<<nb, 256, 0, stream>>>(cntP, degP, cnt, dinv, N, NS);
  k_scan_local<<<nb, 256, 0, stream>>>(cnt, startp, partial, N);
  k_scan_part<<<1, 1024, 0, stream>>>(partial, nb);
  k_scan_add<<<nb, 256, 0, stream>>>(startp, partial, N, E);
  k_fill<<<eb, 256, 0, stream>>>(row, col, eattr, startp, cntP, ord, dinv, emeta, E, N);
  int wtot = L * EMB * EMB;
  k_wsplit<<<(wtot + 255) / 256, 256, 0, stream>>>(lin_W, Wt, wtot);

  int ab = (N + 3) / 4;
  int gb = (N + 127) / 128;
  float* hcur = hbuf;
  for (int l = 0; l < L; ++l) {
    if (l == 0)
      k_agg<1><<<ab, 256, 0, stream>>>(hcur, x, atom_emb, startp, emeta, bond_emb,
                                       Ahi, Alo, N, BV);
    else
      k_agg<0><<<ab, 256, 0, stream>>>(hcur, x, atom_emb, startp, emeta, bond_emb,
                                       Ahi, Alo, N, BV);
    float* hnext = (l == L - 1) ? out : ((hcur == hbuf) ? out : hbuf);
    k_gemm<<<gb, 256, 0, stream>>>(Ahi, Alo, Wt + (size_t)l * 256 * EMB,
                                   lin_b + (size_t)l * EMB, hnext, N);
    hcur = hnext;
  }
}